// Round 4
// baseline (171.749 us; speedup 1.0000x reference)
//
#include <hip/hip_runtime.h>

#define EPSF 1e-5f

typedef int    int4v   __attribute__((ext_vector_type(4)));
typedef float  float4v __attribute__((ext_vector_type(4)));

// ---------- ws layout (weights/constants only; intermediates live in LDS) ----------
// w1p  : i64  [36*3*64]  = 55296 B   (w1 packed MFMA A-fragments)
// w3p  : i64  [6*18*64]  = 55296 B   (w3 packed MFMA B-fragments)
// w2qi : int8 [9][576]   = 5184 B    (dw weights, tap-major)
// s1b1 : f32  [2][576]               (fused BN+requant scale/bias, conv1)
// s2b2 : f32  [2][576]               (dw)
// s3b3 : f32  [2][96]                (conv3, no requant)
#define W1P_OFF  0
#define W3P_OFF  55296
#define W2QI_OFF 110592
#define S1B1_OFF 115776
#define S2B2_OFF 120384
#define S3B3_OFF 124992

__device__ __forceinline__ float lsq_q(float v, float a) {
    float t = v / a;                       // real division (weight alphas not pow2)
    t = fminf(fmaxf(t, -8.0f), 7.0f);
    return rintf(t);                       // RNE == jnp.round
}

__device__ __forceinline__ long q8pack_w(const float* s, float a) {
    unsigned long long v = 0;
    #pragma unroll
    for (int j = 0; j < 8; ++j) {
        int q = (int)lsq_q(s[j], a);
        v |= (unsigned long long)(q & 255) << (8 * j);
    }
    return (long)v;
}

// ---------------- prep: quantize/pack weights + fused epilogue constants ----------------
// Fragment layout (16x16x32 i8, HW-verified r2/r3): lane l holds 8 k-bytes
// k = (l>>4)*8 + j at m/n' = l&15.
__global__ __launch_bounds__(256)
void prep_w(const float* __restrict__ w1, const float* __restrict__ w2,
            const float* __restrict__ w3,
            const float* aw1, const float* ax1, const float* ax2,
            const float* aw2, const float* ax3, const float* aw3,
            const float* __restrict__ g1, const float* __restrict__ b1,
            const float* __restrict__ m1, const float* __restrict__ v1,
            const float* __restrict__ g2, const float* __restrict__ b2,
            const float* __restrict__ m2, const float* __restrict__ v2,
            const float* __restrict__ g3, const float* __restrict__ b3,
            const float* __restrict__ m3, const float* __restrict__ v3,
            long* __restrict__ w1p, long* __restrict__ w3p,
            signed char* __restrict__ w2qi,
            float* __restrict__ s1b1, float* __restrict__ s2b2,
            float* __restrict__ s3b3) {
    int id = blockIdx.x * 256 + threadIdx.x;
    if (id < 6912) {                        // w1p: ct 0..35, kc 0..2
        int l = id & 63, t = id >> 6;
        int kc = t % 3, ct = t / 3;
        int co = ct * 16 + (l & 15);
        int ci0 = kc * 32 + (l >> 4) * 8;
        w1p[id] = q8pack_w(w1 + co * 96 + ci0, aw1[0]);
    } else if (id < 13824) {                // w3p: ct 0..5, kc 0..17
        int i = id - 6912;
        int l = i & 63, t = i >> 6;
        int kc = t % 18, ct = t / 18;
        int co = ct * 16 + (l & 15);
        int ci0 = kc * 32 + (l >> 4) * 8;
        w3p[i] = q8pack_w(w3 + co * 576 + ci0, aw3[0]);
    } else if (id < 19008) {                // w2qi[tap][c] int8
        int i = id - 13824;
        int c = i % 576, tap = i / 576;
        w2qi[i] = (signed char)(int)lsq_q(w2[c * 9 + tap], aw2[0]);
    } else if (id < 19584) {                // conv1 fused constants
        int c = id - 19008;
        float s = g1[c] / sqrtf(v1[c] + EPSF);
        float A = aw1[0] * ax1[0];
        float inv = 1.0f / ax2[0];          // exact (alpha = pow2)
        s1b1[c] = A * s * inv;
        s1b1[576 + c] = (b1[c] - m1[c] * s) * inv;
    } else if (id < 20160) {                // dw fused constants
        int c = id - 19584;
        float s = g2[c] / sqrtf(v2[c] + EPSF);
        float A = ax2[0] * aw2[0];
        float inv = 1.0f / ax3[0];
        s2b2[c] = A * s * inv;
        s2b2[576 + c] = (b2[c] - m2[c] * s) * inv;
    } else if (id < 20256) {                // conv3 fused constants
        int c = id - 20160;
        float s = g3[c] / sqrtf(v3[c] + EPSF);
        float A = ax3[0] * aw3[0];
        s3b3[c] = A * s;
        s3b3[96 + c] = b3[c] - m3[c] * s;
    }
}

// ---------------- fused conv1 -> dw -> conv3, one block per (batch, 2-row strip) ----
// LDS tile h: 112 rows (4 spatial rows x 28 cols, 1-row halo each side) x 576 ch int8,
// row stride 592 B (+16 pad: word-stride 148 === 20 mod 32 -> epilogue store covers all
// 32 banks at 2-way = conflict-free). dw overwrites rows 0..55 in place after a barrier.
__global__ __launch_bounds__(448, 4)
void fused_k(const float* __restrict__ x, const long* __restrict__ w1p,
             const signed char* __restrict__ w2qi, const long* __restrict__ w3p,
             const float* __restrict__ ax1,
             const float* __restrict__ s1b1, const float* __restrict__ s2b2,
             const float* __restrict__ s3b3, float* __restrict__ out) {
    __shared__ __align__(16) signed char h[112 * 592];
    const int tid = threadIdx.x;
    const int w = tid >> 6, l = tid & 63;
    const int quad = l >> 4, c16 = l & 15;
    const int b = blockIdx.x;          // batch 0..31
    const int r0 = blockIdx.y * 2;     // first inner row of strip

    // ---- Phase A: conv1 (i8 MFMA, A=weights B=acts) into LDS ----
    {
        const int lp = w * 16 + c16;                 // 0..111 (wave = n-tile)
        int row = r0 - 1 + lp / 28;                  // halo rows clamped; dw predicates
        row = min(max(row, 0), 27);
        const int p = row * 28 + lp % 28;
        const float inv1 = 1.0f / ax1[0];            // exact for pow2 alpha

        long bfr[3];
        #pragma unroll
        for (int kc = 0; kc < 3; ++kc) {             // quantize 8 input ch per quad
            const float* xs = x + (b * 96 + kc * 32 + quad * 8) * 784 + p;
            unsigned long long v = 0;
            #pragma unroll
            for (int j = 0; j < 8; ++j) {
                float t = xs[j * 784] * inv1;
                t = fminf(fmaxf(t, -8.0f), 7.0f);
                int q = (int)rintf(t);
                v |= (unsigned long long)(q & 255) << (8 * j);
            }
            bfr[kc] = (long)v;
        }
        #pragma unroll 4
        for (int ct = 0; ct < 36; ++ct) {
            int4v acc; acc[0] = 0; acc[1] = 0; acc[2] = 0; acc[3] = 0;
            #pragma unroll
            for (int kc = 0; kc < 3; ++kc)
                acc = __builtin_amdgcn_mfma_i32_16x16x32_i8(
                    w1p[(ct * 3 + kc) * 64 + l], bfr[kc], acc, 0, 0, 0);
            const int co0 = ct * 16 + quad * 4;      // 4 consecutive co per lane
            float4v S = *(const float4v*)(s1b1 + co0);
            float4v B = *(const float4v*)(s1b1 + 576 + co0);
            int pk = 0;
            #pragma unroll
            for (int r = 0; r < 4; ++r) {
                float t = fmaf((float)acc[r], S[r], B[r]);
                t = fminf(fmaxf(t, 0.0f), 7.0f);     // ReLU6 + quant-clip fused
                pk |= ((int)rintf(t)) << (8 * r);
            }
            *(int*)(h + lp * 592 + co0) = pk;        // h1 values in [0,7]
        }
    }
    __syncthreads();

    // ---- Phase B: 3x3 depthwise from LDS (exact int math), stash, overwrite ----
    int res0[9], res1[9];
    #pragma unroll
    for (int i = 0; i < 9; ++i) {                    // 4032 tasks = 448 thr x 9
        const int idx = tid + 448 * i;
        const int pos = idx / 72, g = idx - (idx / 72) * 72;   // pos<56, 8-ch group
        const int row_in = pos / 28, col = pos - (pos / 28) * 28;
        int acc[8] = {0, 0, 0, 0, 0, 0, 0, 0};
        #pragma unroll
        for (int dh = -1; dh <= 1; ++dh) {
            if ((unsigned)(r0 + row_in + dh) >= 28u) continue;
            #pragma unroll
            for (int dc = -1; dc <= 1; ++dc) {
                if ((unsigned)(col + dc) >= 28u) continue;
                const int lp = (row_in + 1 + dh) * 28 + col + dc;
                const int2 xv = *(const int2*)(h + lp * 592 + g * 8);
                const int tap = (dh + 1) * 3 + dc + 1;
                const int w0 = *(const int*)(w2qi + tap * 576 + g * 8);
                const int w1v = *(const int*)(w2qi + tap * 576 + g * 8 + 4);
                #pragma unroll
                for (int j = 0; j < 4; ++j) {        // x unsigned nibble, w sext
                    acc[j]     += ((xv.x >> (8 * j)) & 15) * ((w0  << (24 - 8 * j)) >> 24);
                    acc[4 + j] += ((xv.y >> (8 * j)) & 15) * ((w1v << (24 - 8 * j)) >> 24);
                }
            }
        }
        int pk0 = 0, pk1 = 0;
        #pragma unroll
        for (int j = 0; j < 8; ++j) {
            const int c = g * 8 + j;
            float t = fmaf((float)acc[j], s2b2[c], s2b2[576 + c]);
            t = fminf(fmaxf(t, 0.0f), 7.0f);
            const int q = (int)rintf(t);
            if (j < 4) pk0 |= q << (8 * j); else pk1 |= q << (8 * (j - 4));
        }
        res0[i] = pk0; res1[i] = pk1;
    }
    __syncthreads();                                  // all h1 reads done
    #pragma unroll
    for (int i = 0; i < 9; ++i) {
        const int idx = tid + 448 * i;
        const int pos = idx / 72, g = idx - (idx / 72) * 72;
        int2 pk; pk.x = res0[i]; pk.y = res1[i];
        *(int2*)(h + pos * 592 + g * 8) = pk;         // h2 rows 0..55 in place
    }
    __syncthreads();

    // ---- Phase C: conv3 (i8 MFMA, A=h2 B=weights) + BN + residual ----
    // 24 tasks = 4 n-tiles (56 pos padded to 64) x 6 co-tiles, round-robin over waves.
    for (int t = w; t < 24; t += 7) {
        const int nt = t / 6, ct = t - (t / 6) * 6;
        int4v acc; acc[0] = 0; acc[1] = 0; acc[2] = 0; acc[3] = 0;
        const signed char* arow = h + (nt * 16 + c16) * 592 + quad * 8;
        #pragma unroll 6
        for (int kc = 0; kc < 18; ++kc)
            acc = __builtin_amdgcn_mfma_i32_16x16x32_i8(
                *(const long*)(arow + kc * 32),
                w3p[(ct * 18 + kc) * 64 + l], acc, 0, 0, 0);
        const int nloc = nt * 16 + quad * 4;          // 4 consecutive positions
        if (nloc < 56) {                              // tile 3 upper half = padding
            const int co = ct * 16 + c16;
            const float S = s3b3[co], Bv = s3b3[96 + co];
            const int off = (b * 96 + co) * 784 + r0 * 28 + nloc;  // 16B-aligned
            const float4v xr = *(const float4v*)(x + off);
            float4v o;
            #pragma unroll
            for (int r = 0; r < 4; ++r)
                o[r] = fmaf((float)acc[r], S, Bv) + xr[r];
            *(float4v*)(out + off) = o;
        }
    }
}

extern "C" void kernel_launch(void* const* d_in, const int* in_sizes, int n_in,
                              void* d_out, int out_size, void* d_ws, size_t ws_size,
                              hipStream_t stream) {
    const float* x   = (const float*)d_in[0];
    const float* w1  = (const float*)d_in[1];
    const float* w2  = (const float*)d_in[2];
    const float* w3  = (const float*)d_in[3];
    const float* aw1 = (const float*)d_in[4];
    const float* ax1 = (const float*)d_in[5];
    const float* g1  = (const float*)d_in[6];
    const float* b1  = (const float*)d_in[7];
    const float* m1  = (const float*)d_in[8];
    const float* v1  = (const float*)d_in[9];
    const float* aw2 = (const float*)d_in[10];
    const float* ax2 = (const float*)d_in[11];
    const float* g2  = (const float*)d_in[12];
    const float* b2  = (const float*)d_in[13];
    const float* m2  = (const float*)d_in[14];
    const float* v2  = (const float*)d_in[15];
    const float* aw3 = (const float*)d_in[16];
    const float* ax3 = (const float*)d_in[17];
    const float* g3  = (const float*)d_in[18];
    const float* b3  = (const float*)d_in[19];
    const float* m3  = (const float*)d_in[20];
    const float* v3  = (const float*)d_in[21];

    char* ws = (char*)d_ws;
    long* w1p = (long*)(ws + W1P_OFF);
    long* w3p = (long*)(ws + W3P_OFF);
    signed char* w2qi = (signed char*)(ws + W2QI_OFF);
    float* s1b1 = (float*)(ws + S1B1_OFF);
    float* s2b2 = (float*)(ws + S2B2_OFF);
    float* s3b3 = (float*)(ws + S3B3_OFF);

    float* out = (float*)d_out;

    prep_w<<<80, 256, 0, stream>>>(w1, w2, w3, aw1, ax1, ax2, aw2, ax3, aw3,
                                   g1, b1, m1, v1, g2, b2, m2, v2, g3, b3, m3, v3,
                                   w1p, w3p, w2qi, s1b1, s2b2, s3b3);
    dim3 grid(32, 14);
    fused_k<<<grid, 448, 0, stream>>>(x, w1p, w2qi, w3p, ax1, s1b1, s2b2, s3b3, out);
}

// Round 5
// 151.751 us; speedup vs baseline: 1.1318x; 1.1318x over previous
//
#include <hip/hip_runtime.h>

#define EPSF 1e-5f

typedef int    int4v   __attribute__((ext_vector_type(4)));
typedef float  float4v __attribute__((ext_vector_type(4)));

// ---------- ws layout (weights/constants only; intermediates live in LDS) ----------
#define W1P_OFF  0
#define W3P_OFF  55296
#define W2QI_OFF 110592
#define S1B1_OFF 115776
#define S2B2_OFF 120384
#define S3B3_OFF 124992

// LDS strides (bytes). h1 nibble-packed: 576 ch -> 288 B + 8 pad = 296 (74 w === 10 mod 32,
// 16 lanes -> 16 distinct banks). h2 int8: 576 B + 24 pad = 600 (150 w === 22 mod 32, gcd 2:
// 16 lanes x b64 cover all 32 banks at the 4-cycle minimum -> conflict-free).
#define H1S 296
#define H2S 600

__device__ __forceinline__ float lsq_q(float v, float a) {
    float t = v / a;                       // real division (weight alphas not pow2)
    t = fminf(fmaxf(t, -8.0f), 7.0f);
    return rintf(t);                       // RNE == jnp.round
}

__device__ __forceinline__ long q8pack_w(const float* s, float a) {
    unsigned long long v = 0;
    #pragma unroll
    for (int j = 0; j < 8; ++j) {
        int q = (int)lsq_q(s[j], a);
        v |= (unsigned long long)(q & 255) << (8 * j);
    }
    return (long)v;
}

// ---------------- prep: quantize/pack weights + fused epilogue constants ----------------
// Fragment layout (16x16x32 i8, HW-verified r2-r4): lane l holds 8 k-bytes
// k = (l>>4)*8 + j at m/n' = l&15.
__global__ __launch_bounds__(256)
void prep_w(const float* __restrict__ w1, const float* __restrict__ w2,
            const float* __restrict__ w3,
            const float* aw1, const float* ax1, const float* ax2,
            const float* aw2, const float* ax3, const float* aw3,
            const float* __restrict__ g1, const float* __restrict__ b1,
            const float* __restrict__ m1, const float* __restrict__ v1,
            const float* __restrict__ g2, const float* __restrict__ b2,
            const float* __restrict__ m2, const float* __restrict__ v2,
            const float* __restrict__ g3, const float* __restrict__ b3,
            const float* __restrict__ m3, const float* __restrict__ v3,
            long* __restrict__ w1p, long* __restrict__ w3p,
            signed char* __restrict__ w2qi,
            float* __restrict__ s1b1, float* __restrict__ s2b2,
            float* __restrict__ s3b3) {
    int id = blockIdx.x * 256 + threadIdx.x;
    if (id < 6912) {                        // w1p: ct 0..35, kc 0..2
        int l = id & 63, t = id >> 6;
        int kc = t % 3, ct = t / 3;
        int co = ct * 16 + (l & 15);
        int ci0 = kc * 32 + (l >> 4) * 8;
        w1p[id] = q8pack_w(w1 + co * 96 + ci0, aw1[0]);
    } else if (id < 13824) {                // w3p: ct 0..5, kc 0..17
        int i = id - 6912;
        int l = i & 63, t = i >> 6;
        int kc = t % 18, ct = t / 18;
        int co = ct * 16 + (l & 15);
        int ci0 = kc * 32 + (l >> 4) * 8;
        w3p[i] = q8pack_w(w3 + co * 576 + ci0, aw3[0]);
    } else if (id < 19008) {                // w2qi[tap][c] int8
        int i = id - 13824;
        int c = i % 576, tap = i / 576;
        w2qi[i] = (signed char)(int)lsq_q(w2[c * 9 + tap], aw2[0]);
    } else if (id < 19584) {                // conv1 fused constants
        int c = id - 19008;
        float s = g1[c] / sqrtf(v1[c] + EPSF);
        float A = aw1[0] * ax1[0];
        float inv = 1.0f / ax2[0];          // exact (alpha = pow2)
        s1b1[c] = A * s * inv;
        s1b1[576 + c] = (b1[c] - m1[c] * s) * inv;
    } else if (id < 20160) {                // dw fused constants
        int c = id - 19584;
        float s = g2[c] / sqrtf(v2[c] + EPSF);
        float A = ax2[0] * aw2[0];
        float inv = 1.0f / ax3[0];
        s2b2[c] = A * s * inv;
        s2b2[576 + c] = (b2[c] - m2[c] * s) * inv;
    } else if (id < 20256) {                // conv3 fused constants
        int c = id - 20160;
        float s = g3[c] / sqrtf(v3[c] + EPSF);
        float A = ax3[0] * aw3[0];
        s3b3[c] = A * s;
        s3b3[96 + c] = b3[c] - m3[c] * s;
    }
}

// ---------------- fused conv1 -> dw -> conv3, one block per (batch, 2-row strip) ----
// Phase A: conv1 MFMA -> h1 (nibbles, [0,7]).  Phase B: 3x3 dw from h1 -> h2 (int8,
// separate buffer: no stash, no extra barrier).  Phase C: conv3 MFMA from h2 + residual.
__global__ __launch_bounds__(448, 4)
void fused_k(const float* __restrict__ x, const long* __restrict__ w1p,
             const signed char* __restrict__ w2qi, const long* __restrict__ w3p,
             const float* __restrict__ ax1,
             const float* __restrict__ s1b1, const float* __restrict__ s2b2,
             const float* __restrict__ s3b3, float* __restrict__ out) {
    __shared__ __align__(16) signed char h1[112 * H1S];   // 33.2 KB, nibble-packed
    __shared__ __align__(16) signed char h2[64 * H2S];    // 38.4 KB (rows 56..63 pad)
    const int tid = threadIdx.x;
    const int w = tid >> 6, l = tid & 63;
    const int quad = l >> 4, c16 = l & 15;
    const int b = blockIdx.x;          // batch 0..31
    const int r0 = blockIdx.y * 2;     // first inner row of strip

    // ---- Phase A: conv1 (i8 MFMA, A=weights B=acts) -> h1 nibbles ----
    {
        const int lp = w * 16 + c16;                 // 0..111 (wave = n-tile)
        int row = r0 - 1 + lp / 28;                  // halo rows clamped; dw predicates
        row = min(max(row, 0), 27);
        const int p = row * 28 + lp % 28;
        const float inv1 = 1.0f / ax1[0];            // exact for pow2 alpha

        long bfr[3];
        #pragma unroll
        for (int kc = 0; kc < 3; ++kc) {             // quantize 8 input ch per quad
            const float* xs = x + (b * 96 + kc * 32 + quad * 8) * 784 + p;
            unsigned long long v = 0;
            #pragma unroll
            for (int j = 0; j < 8; ++j) {
                float t = xs[j * 784] * inv1;
                t = fminf(fmaxf(t, -8.0f), 7.0f);
                int q = (int)rintf(t);
                v |= (unsigned long long)(q & 255) << (8 * j);
            }
            bfr[kc] = (long)v;
        }
        #pragma unroll 4
        for (int ct = 0; ct < 36; ++ct) {
            int4v acc; acc[0] = 0; acc[1] = 0; acc[2] = 0; acc[3] = 0;
            #pragma unroll
            for (int kc = 0; kc < 3; ++kc)
                acc = __builtin_amdgcn_mfma_i32_16x16x32_i8(
                    w1p[(ct * 3 + kc) * 64 + l], bfr[kc], acc, 0, 0, 0);
            const int co0 = ct * 16 + quad * 4;      // 4 consecutive co per lane
            float4v S = *(const float4v*)(s1b1 + co0);
            float4v B = *(const float4v*)(s1b1 + 576 + co0);
            int pk = 0;
            #pragma unroll
            for (int r = 0; r < 4; ++r) {
                float t = fmaf((float)acc[r], S[r], B[r]);
                t = fminf(fmaxf(t, 0.0f), 7.0f);     // ReLU6 + quant-clip fused
                pk |= ((int)rintf(t)) << (4 * r);    // nibble pack (values 0..7)
            }
            *(unsigned short*)(h1 + lp * H1S + (co0 >> 1)) = (unsigned short)pk;
        }
    }
    __syncthreads();

    // ---- Phase B: 3x3 depthwise from h1 nibbles (exact int math) -> h2 int8 ----
    #pragma unroll
    for (int i = 0; i < 9; ++i) {                    // 4032 tasks = 448 thr x 9
        const int idx = tid + 448 * i;
        const int pos = idx / 72, g = idx - (idx / 72) * 72;   // pos<56, 8-ch group
        const int row_in = pos / 28, col = pos - (pos / 28) * 28;
        int acc[8] = {0, 0, 0, 0, 0, 0, 0, 0};
        #pragma unroll
        for (int dh = -1; dh <= 1; ++dh) {
            if ((unsigned)(r0 + row_in + dh) >= 28u) continue;
            #pragma unroll
            for (int dc = -1; dc <= 1; ++dc) {
                if ((unsigned)(col + dc) >= 28u) continue;
                const int lp = (row_in + 1 + dh) * 28 + col + dc;
                const unsigned int xv = *(const unsigned int*)(h1 + lp * H1S + g * 4);
                const int tap = (dh + 1) * 3 + dc + 1;
                const int w0  = *(const int*)(w2qi + tap * 576 + g * 8);
                const int w1v = *(const int*)(w2qi + tap * 576 + g * 8 + 4);
                #pragma unroll
                for (int j = 0; j < 4; ++j) {        // x unsigned nibble, w sext
                    acc[j]     += (int)((xv >> (4 * j)) & 15u)       * ((w0  << (24 - 8 * j)) >> 24);
                    acc[4 + j] += (int)((xv >> (4 * (4 + j))) & 15u) * ((w1v << (24 - 8 * j)) >> 24);
                }
            }
        }
        int pk0 = 0, pk1 = 0;
        #pragma unroll
        for (int j = 0; j < 8; ++j) {
            const int c = g * 8 + j;
            float t = fmaf((float)acc[j], s2b2[c], s2b2[576 + c]);
            t = fminf(fmaxf(t, 0.0f), 7.0f);
            const int q = (int)rintf(t);
            if (j < 4) pk0 |= q << (8 * j); else pk1 |= q << (8 * (j - 4));
        }
        int2 pk; pk.x = pk0; pk.y = pk1;
        *(int2*)(h2 + pos * H2S + g * 8) = pk;
    }
    __syncthreads();

    // ---- Phase C: conv3 (i8 MFMA, A=h2 B=weights) + BN + residual ----
    // 24 tasks = 4 n-tiles (56 pos padded to 64) x 6 co-tiles, round-robin over waves.
    for (int t = w; t < 24; t += 7) {
        const int nt = t / 6, ct = t - (t / 6) * 6;
        int4v acc; acc[0] = 0; acc[1] = 0; acc[2] = 0; acc[3] = 0;
        const signed char* arow = h2 + (nt * 16 + c16) * H2S + quad * 8;
        #pragma unroll 6
        for (int kc = 0; kc < 18; ++kc)
            acc = __builtin_amdgcn_mfma_i32_16x16x32_i8(
                *(const long*)(arow + kc * 32),
                w3p[(ct * 18 + kc) * 64 + l], acc, 0, 0, 0);
        const int nloc = nt * 16 + quad * 4;          // 4 consecutive positions
        if (nloc < 56) {                              // tile 3 upper half = padding
            const int co = ct * 16 + c16;
            const float S = s3b3[co], Bv = s3b3[96 + co];
            const int off = (b * 96 + co) * 784 + r0 * 28 + nloc;  // 16B-aligned
            const float4v xr = *(const float4v*)(x + off);
            float4v o;
            #pragma unroll
            for (int r = 0; r < 4; ++r)
                o[r] = fmaf((float)acc[r], S, Bv) + xr[r];
            *(float4v*)(out + off) = o;
        }
    }
}

extern "C" void kernel_launch(void* const* d_in, const int* in_sizes, int n_in,
                              void* d_out, int out_size, void* d_ws, size_t ws_size,
                              hipStream_t stream) {
    const float* x   = (const float*)d_in[0];
    const float* w1  = (const float*)d_in[1];
    const float* w2  = (const float*)d_in[2];
    const float* w3  = (const float*)d_in[3];
    const float* aw1 = (const float*)d_in[4];
    const float* ax1 = (const float*)d_in[5];
    const float* g1  = (const float*)d_in[6];
    const float* b1  = (const float*)d_in[7];
    const float* m1  = (const float*)d_in[8];
    const float* v1  = (const float*)d_in[9];
    const float* aw2 = (const float*)d_in[10];
    const float* ax2 = (const float*)d_in[11];
    const float* g2  = (const float*)d_in[12];
    const float* b2  = (const float*)d_in[13];
    const float* m2  = (const float*)d_in[14];
    const float* v2  = (const float*)d_in[15];
    const float* aw3 = (const float*)d_in[16];
    const float* ax3 = (const float*)d_in[17];
    const float* g3  = (const float*)d_in[18];
    const float* b3  = (const float*)d_in[19];
    const float* m3  = (const float*)d_in[20];
    const float* v3  = (const float*)d_in[21];

    char* ws = (char*)d_ws;
    long* w1p = (long*)(ws + W1P_OFF);
    long* w3p = (long*)(ws + W3P_OFF);
    signed char* w2qi = (signed char*)(ws + W2QI_OFF);
    float* s1b1 = (float*)(ws + S1B1_OFF);
    float* s2b2 = (float*)(ws + S2B2_OFF);
    float* s3b3 = (float*)(ws + S3B3_OFF);

    float* out = (float*)d_out;

    prep_w<<<80, 256, 0, stream>>>(w1, w2, w3, aw1, ax1, ax2, aw2, ax3, aw3,
                                   g1, b1, m1, v1, g2, b2, m2, v2, g3, b3, m3, v3,
                                   w1p, w3p, w2qi, s1b1, s2b2, s3b3);
    dim3 grid(32, 14);
    fused_k<<<grid, 448, 0, stream>>>(x, w1p, w2qi, w3p, ax1, s1b1, s2b2, s3b3, out);
}

// Round 6
// 144.984 us; speedup vs baseline: 1.1846x; 1.0467x over previous
//
#include <hip/hip_runtime.h>

#define EPSF 1e-5f

typedef int    int4v   __attribute__((ext_vector_type(4)));
typedef float  float4v __attribute__((ext_vector_type(4)));

// ---------- ws layout (weights/constants only; intermediates live in LDS) ----------
// w1p : i64 [36*3*64]   conv1 A-fragments (m=co)
// w3p : i64 [6*18*64]   conv3 B-fragments (n=co)
// w2d : i64 [36*5*64]   dw diagonal A-fragments (m=ch_local, k=(tap,c'), nibble-perm folded)
#define W1P_OFF  0
#define W3P_OFF  55296
#define W2D_OFF  110592
#define S1B1_OFF 202752
#define S2B2_OFF 207360
#define S3B3_OFF 211968

// LDS strides (bytes).
// h1 nibble-packed, rows of 30 positions (zero halo cols): 576ch -> 288B +8 pad = 296
//   (74 w === 10 mod 32: 16-lane stride-74 word access -> 16 distinct banks, quads 2-way = free)
// h2 int8: 576B + 24 pad = 600 (150 w === 22 mod 32: b32/b64 patterns cover banks evenly = free)
#define H1S 296
#define H2S 600

__device__ __forceinline__ float lsq_q(float v, float a) {
    float t = v / a;                       // real division (weight alphas not pow2)
    t = fminf(fmaxf(t, -8.0f), 7.0f);
    return rintf(t);                       // RNE == jnp.round
}

__device__ __forceinline__ long q8pack_w(const float* w, int base, const int* idx, float a) {
    unsigned long long v = 0;
    #pragma unroll
    for (int j = 0; j < 8; ++j) {
        int q = (int)lsq_q(w[base + idx[j]], a);
        v |= (unsigned long long)(q & 255) << (8 * j);
    }
    return (long)v;
}

// ---------------- prep: quantize/pack weights + fused epilogue constants ----------------
// i8 MFMA 16x16x32 fragment layout (HW-verified r2-r5): lane l holds 8 k-bytes
// k = (l>>4)*8 + j at m/n = l&15;  D: col = l&15, row = (l>>4)*4 + reg.
__global__ __launch_bounds__(256)
void prep_w(const float* __restrict__ w1, const float* __restrict__ w2,
            const float* __restrict__ w3,
            const float* aw1, const float* ax1, const float* ax2,
            const float* aw2, const float* ax3, const float* aw3,
            const float* __restrict__ g1, const float* __restrict__ b1,
            const float* __restrict__ m1, const float* __restrict__ v1,
            const float* __restrict__ g2, const float* __restrict__ b2,
            const float* __restrict__ m2, const float* __restrict__ v2,
            const float* __restrict__ g3, const float* __restrict__ b3,
            const float* __restrict__ m3, const float* __restrict__ v3,
            long* __restrict__ w1p, long* __restrict__ w3p,
            long* __restrict__ w2d,
            float* __restrict__ s1b1, float* __restrict__ s2b2,
            float* __restrict__ s3b3) {
    int id = blockIdx.x * 256 + threadIdx.x;
    const int lin[8] = {0, 1, 2, 3, 4, 5, 6, 7};
    if (id < 6912) {                        // w1p: ct 0..35, kc 0..2
        int l = id & 63, t = id >> 6;
        int kc = t % 3, ct = t / 3;
        int co = ct * 16 + (l & 15);
        int ci0 = kc * 32 + (l >> 4) * 8;
        w1p[id] = q8pack_w(w1, co * 96 + ci0, lin, aw1[0]);
    } else if (id < 13824) {                // w3p: ct 0..5, kc 0..17
        int i = id - 6912;
        int l = i & 63, t = i >> 6;
        int kc = t % 18, ct = t / 18;
        int co = ct * 16 + (l & 15);
        int ci0 = kc * 32 + (l >> 4) * 8;
        w3p[i] = q8pack_w(w3, co * 576 + ci0, lin, aw3[0]);
    } else if (id < 25344) {                // w2d: (ct*5 + kc)*64 + l
        int i = id - 13824;
        int l = i & 63, t = i >> 6;
        int kc = t % 5, ct = t / 5;
        int quad = l >> 4, m = l & 15;
        int tap = kc * 2 + (quad >> 1);
        unsigned long long v = 0;
        if (tap <= 8) {
            int mh = m - (quad & 1) * 8;    // lane's channel within this quad's octet?
            if (mh >= 0 && mh < 8) {
                // byte j whose k-channel c' = (quad&1)*8 + 2*(j&3) + (j>>2) equals m
                int j = (mh >> 1) | ((mh & 1) << 2);
                int q = (int)lsq_q(w2[(ct * 16 + m) * 9 + tap], aw2[0]);
                v = (unsigned long long)(unsigned)(q & 255) << (8 * j);
            }
        }
        w2d[i] = (long)v;
    } else if (id < 25920) {                // conv1 fused constants
        int c = id - 25344;
        float s = g1[c] / sqrtf(v1[c] + EPSF);
        float A = aw1[0] * ax1[0];
        float inv = 1.0f / ax2[0];          // exact (alpha = pow2)
        s1b1[c] = A * s * inv;
        s1b1[576 + c] = (b1[c] - m1[c] * s) * inv;
    } else if (id < 26496) {                // dw fused constants
        int c = id - 25920;
        float s = g2[c] / sqrtf(v2[c] + EPSF);
        float A = ax2[0] * aw2[0];
        float inv = 1.0f / ax3[0];
        s2b2[c] = A * s * inv;
        s2b2[576 + c] = (b2[c] - m2[c] * s) * inv;
    } else if (id < 26592) {                // conv3 fused constants
        int c = id - 26496;
        float s = g3[c] / sqrtf(v3[c] + EPSF);
        float A = ax3[0] * aw3[0];
        s3b3[c] = A * s;
        s3b3[96 + c] = b3[c] - m3[c] * s;
    }
}

// ---------------- fused conv1 -> dw(MFMA) -> conv3, block = (batch, 2-row strip) ----
__global__ __launch_bounds__(448, 4)
void fused_k(const float* __restrict__ x, const long* __restrict__ w1p,
             const long* __restrict__ w2d, const long* __restrict__ w3p,
             const float* __restrict__ ax1,
             const float* __restrict__ s1b1, const float* __restrict__ s2b2,
             const float* __restrict__ s3b3, float* __restrict__ out) {
    __shared__ __align__(16) signed char h1[120 * H1S];   // 4 rows x 30 cols, nibbles
    __shared__ __align__(16) signed char h2[64 * H2S];    // 56 pos + 8 pad rows, int8
    const int tid = threadIdx.x;
    const int w = tid >> 6, l = tid & 63;
    const int quad = l >> 4, c16 = l & 15;
    const int qh = quad >> 1, ql = quad & 1;
    const int b = blockIdx.x;          // batch 0..31
    const int r0 = blockIdx.y * 2;     // first output row of strip

    // zero h1 (halo cols/rows must read as 0 in Phase B)
    for (int i = tid; i < 120 * H1S / 16; i += 448)
        ((int4v*)h1)[i] = (int4v){0, 0, 0, 0};
    __syncthreads();

    // ---- Phase A: conv1 (i8 MFMA, A=weights B=acts) -> h1 nibbles ----
    {
        const int lp = w * 16 + c16;                 // 0..111: row 0..3, col 0..27
        const int row = lp / 28, col = lp - (lp / 28) * 28;
        const int img_row = r0 - 1 + row;
        const bool valid = (unsigned)img_row < 28u;
        const int p = min(max(img_row, 0), 27) * 28 + col;
        const float inv1 = 1.0f / ax1[0];            // exact for pow2 alpha

        long bfr[3];
        #pragma unroll
        for (int kc = 0; kc < 3; ++kc) {             // quantize 8 input ch per quad
            const float* xs = x + (b * 96 + kc * 32 + quad * 8) * 784 + p;
            unsigned long long v = 0;
            #pragma unroll
            for (int j = 0; j < 8; ++j) {
                float t = xs[j * 784] * inv1;
                t = fminf(fmaxf(t, -8.0f), 7.0f);
                int q = (int)rintf(t);
                v |= (unsigned long long)(q & 255) << (8 * j);
            }
            bfr[kc] = (long)v;
        }
        const int pos_h = row * 30 + col + 1;        // halo-extended index
        #pragma unroll 4
        for (int ct = 0; ct < 36; ++ct) {
            int4v acc; acc[0] = 0; acc[1] = 0; acc[2] = 0; acc[3] = 0;
            #pragma unroll
            for (int kc = 0; kc < 3; ++kc)
                acc = __builtin_amdgcn_mfma_i32_16x16x32_i8(
                    w1p[(ct * 3 + kc) * 64 + l], bfr[kc], acc, 0, 0, 0);
            const int co0 = ct * 16 + quad * 4;      // 4 consecutive co per lane
            float4v S = *(const float4v*)(s1b1 + co0);
            float4v B = *(const float4v*)(s1b1 + 576 + co0);
            int pk = 0;
            #pragma unroll
            for (int r = 0; r < 4; ++r) {
                float t = fmaf((float)acc[r], S[r], B[r]);
                t = fminf(fmaxf(t, 0.0f), 7.0f);     // ReLU6 + quant-clip fused
                pk |= ((int)rintf(t)) << (4 * r);    // nibble pack (values 0..7)
            }
            if (valid)
                *(unsigned short*)(h1 + pos_h * H1S + (co0 >> 1)) = (unsigned short)pk;
        }
    }
    __syncthreads();

    // ---- Phase B: 3x3 depthwise as block-diagonal i8 MFMA (K=144, 5 chunks) ----
    // A = w2d diag frags (m=ch_local), B = gathered h1 nibbles (n=pos).
    // D: lane holds channels ct*16+quad*4..+3 at pos = l&15 -> b32 store to h2.
    for (int t = w; t < 144; t += 7) {
        const int pt = t / 36, ct = t - (t / 36) * 36;
        const int pos = pt * 16 + c16;               // 0..63 (56 valid)
        const int posc = min(pos, 55);
        const int row_in = posc / 28, col = posc - (posc / 28) * 28;
        const int choff = ct * 8 + ql * 4;           // byte offset of this quad's octet
        int4v acc; acc[0] = 0; acc[1] = 0; acc[2] = 0; acc[3] = 0;
        #pragma unroll
        for (int kc = 0; kc < 5; ++kc) {
            int tap = kc * 2 + qh;
            tap = min(tap, 8);                       // kc=4 quads 2,3: zero weight anyway
            const int dh = tap / 3 - 1, dc = tap - (tap / 3) * 3 - 1;
            const int pos_h = (row_in + 1 + dh) * 30 + (col + 1 + dc);
            const unsigned v = *(const unsigned*)(h1 + pos_h * H1S + choff);
            const unsigned lo = v & 0x0F0F0F0Fu;
            const unsigned hi = (v >> 4) & 0x0F0F0F0Fu;
            const long bf = (long)(((unsigned long long)hi << 32) | lo);
            acc = __builtin_amdgcn_mfma_i32_16x16x32_i8(
                w2d[(ct * 5 + kc) * 64 + l], bf, acc, 0, 0, 0);
        }
        if (pos < 56) {
            const int c0 = ct * 16 + quad * 4;
            float4v S = *(const float4v*)(s2b2 + c0);
            float4v B = *(const float4v*)(s2b2 + 576 + c0);
            int pk = 0;
            #pragma unroll
            for (int r = 0; r < 4; ++r) {
                float tt = fmaf((float)acc[r], S[r], B[r]);
                tt = fminf(fmaxf(tt, 0.0f), 7.0f);
                pk |= ((int)rintf(tt)) << (8 * r);
            }
            *(int*)(h2 + pos * H2S + c0) = pk;
        }
    }
    __syncthreads();

    // ---- Phase C: conv3 (i8 MFMA, A=h2 B=weights) + BN + residual ----
    for (int t = w; t < 24; t += 7) {
        const int nt = t / 6, ct = t - (t / 6) * 6;
        int4v acc; acc[0] = 0; acc[1] = 0; acc[2] = 0; acc[3] = 0;
        const signed char* arow = h2 + (nt * 16 + c16) * H2S + quad * 8;
        #pragma unroll 6
        for (int kc = 0; kc < 18; ++kc)
            acc = __builtin_amdgcn_mfma_i32_16x16x32_i8(
                *(const long*)(arow + kc * 32),
                w3p[(ct * 18 + kc) * 64 + l], acc, 0, 0, 0);
        const int nloc = nt * 16 + quad * 4;          // 4 consecutive positions
        if (nloc < 56) {
            const int co = ct * 16 + c16;
            const float S = s3b3[co], Bv = s3b3[96 + co];
            const int off = (b * 96 + co) * 784 + r0 * 28 + nloc;  // 16B-aligned
            const float4v xr = *(const float4v*)(x + off);
            float4v o;
            #pragma unroll
            for (int r = 0; r < 4; ++r)
                o[r] = fmaf((float)acc[r], S, Bv) + xr[r];
            *(float4v*)(out + off) = o;
        }
    }
}

extern "C" void kernel_launch(void* const* d_in, const int* in_sizes, int n_in,
                              void* d_out, int out_size, void* d_ws, size_t ws_size,
                              hipStream_t stream) {
    const float* x   = (const float*)d_in[0];
    const float* w1  = (const float*)d_in[1];
    const float* w2  = (const float*)d_in[2];
    const float* w3  = (const float*)d_in[3];
    const float* aw1 = (const float*)d_in[4];
    const float* ax1 = (const float*)d_in[5];
    const float* g1  = (const float*)d_in[6];
    const float* b1  = (const float*)d_in[7];
    const float* m1  = (const float*)d_in[8];
    const float* v1  = (const float*)d_in[9];
    const float* aw2 = (const float*)d_in[10];
    const float* ax2 = (const float*)d_in[11];
    const float* g2  = (const float*)d_in[12];
    const float* b2  = (const float*)d_in[13];
    const float* m2  = (const float*)d_in[14];
    const float* v2  = (const float*)d_in[15];
    const float* aw3 = (const float*)d_in[16];
    const float* ax3 = (const float*)d_in[17];
    const float* g3  = (const float*)d_in[18];
    const float* b3  = (const float*)d_in[19];
    const float* m3  = (const float*)d_in[20];
    const float* v3  = (const float*)d_in[21];

    char* ws = (char*)d_ws;
    long* w1p = (long*)(ws + W1P_OFF);
    long* w3p = (long*)(ws + W3P_OFF);
    long* w2d = (long*)(ws + W2D_OFF);
    float* s1b1 = (float*)(ws + S1B1_OFF);
    float* s2b2 = (float*)(ws + S2B2_OFF);
    float* s3b3 = (float*)(ws + S3B3_OFF);

    float* out = (float*)d_out;

    prep_w<<<104, 256, 0, stream>>>(w1, w2, w3, aw1, ax1, ax2, aw2, ax3, aw3,
                                    g1, b1, m1, v1, g2, b2, m2, v2, g3, b3, m3, v3,
                                    w1p, w3p, w2d, s1b1, s2b2, s3b3);
    dim3 grid(32, 14);
    fused_k<<<grid, 448, 0, stream>>>(x, w1p, w2d, w3p, ax1, s1b1, s2b2, s3b3, out);
}